// Round 7
// baseline (583.509 us; speedup 1.0000x reference)
//
#include <hip/hip_runtime.h>

// Problem constants
#define BATCH 8
#define HH 56
#define WW 56
#define NPOS (BATCH*HH*WW)   // 25088
#define C 256
#define P 32
#define D 4
#define J 128
#define EPS 1e-3f
#define H2S 136   // h2s stride in shorts

typedef __attribute__((ext_vector_type(8))) short bf16x8_t;
typedef __attribute__((ext_vector_type(4))) float f32x4_t;

__device__ __forceinline__ unsigned short f2bf(float f) {
    union { float f; unsigned int i; } v; v.f = f;
    unsigned int r = v.i + 0x7fffu + ((v.i >> 16) & 1u);   // RNE
    return (unsigned short)(r >> 16);
}
__device__ __forceinline__ uint2 pack4_trunc(float4 v) {
    uint2 r;
    r.x = __builtin_amdgcn_perm(__float_as_uint(v.y), __float_as_uint(v.x), 0x07060302u);
    r.y = __builtin_amdgcn_perm(__float_as_uint(v.w), __float_as_uint(v.z), 0x07060302u);
    return r;
}

// ---------------------------------------------------------------------------
// Fold BN into conv weights/biases (unchanged).
// ---------------------------------------------------------------------------
__global__ __launch_bounds__(256) void fold_params(
    const float* __restrict__ W1, const float* __restrict__ B1,
    const float* __restrict__ W2, const float* __restrict__ B2,
    const float* __restrict__ W3, const float* __restrict__ B3,
    const float* __restrict__ G1, const float* __restrict__ Be1,
    const float* __restrict__ M1, const float* __restrict__ V1,
    const float* __restrict__ G2, const float* __restrict__ Be2,
    const float* __restrict__ M2, const float* __restrict__ V2,
    const float* __restrict__ G3, const float* __restrict__ Be3,
    const float* __restrict__ M3, const float* __restrict__ V3,
    unsigned short* __restrict__ W1bf, float* __restrict__ b1f,
    float* __restrict__ w2q, float* __restrict__ b2t,
    unsigned short* __restrict__ WB, unsigned short* __restrict__ zb)
{
    int idx = blockIdx.x * 256 + threadIdx.x;

    if (idx < C*J) {                       // W1bf[j][c]
        int j = idx >> 8, c = idx & 255;
        int p = j >> 2, d = j & 3;
        float s = G1[j] * rsqrtf(V1[j] + EPS);
        W1bf[idx] = f2bf(W1[(p*C + c)*D + d] * s);
        return;
    }
    idx -= C*J;
    if (idx < J) {
        float s = G1[idx] * rsqrtf(V1[idx] + EPS);
        b1f[idx] = B1[idx] * s + Be1[idx] - M1[idx] * s;
        return;
    }
    idx -= J;
    if (idx < 9*D*D*P) {                   // w2q [(k9*4+di)*128 + p*4 + do]
        int do_ = idx & 3, p = (idx >> 2) & 31;
        int r2 = idx >> 7, di = r2 & 3, k9 = r2 >> 2;
        int j = p*4 + do_;
        float s = G2[j] * rsqrtf(V2[j] + EPS);
        w2q[idx] = W2[((p*9 + k9)*4 + di)*4 + do_] * s;
        return;
    }
    idx -= 9*D*D*P;
    if (idx < J) {                         // b2t[do][p]
        int do_ = idx >> 5, p = idx & 31;
        int j = p*4 + do_;
        float s = G2[j] * rsqrtf(V2[j] + EPS);
        b2t[idx] = B2[j] * s + Be2[j] - M2[j] * s;
        return;
    }
    idx -= J;
    if (idx < P*C*8) {                     // WB[p][c][s] = {w0..w3, bias, 0,0,0}
        int s8 = idx & 7;
        int c = (idx >> 3) & 255;
        int p = idx >> 11;
        float sc = G3[p*C + c] * rsqrtf(V3[p*C + c] + EPS);
        float v = 0.f;
        if (s8 < 4)       v = W3[(p*D + s8)*C + c] * sc;
        else if (s8 == 4) v = B3[p*C + c] * sc + Be3[p*C + c] - M3[p*C + c] * sc;
        WB[idx] = f2bf(v);
        return;
    }
    idx -= P*C*8;
    if (idx < 8) { zb[idx] = 0; return; }  // 16B zero block
}

// ---------------------------------------------------------------------------
// Fully fused, latency-attack version.
// r6 skeleton: tile 4x4 interior / 6x6 halo, 1568 blocks XCD-swizzled,
// 2 barriers, wave-local B->C. New: (1) w2q/b1f/b2t staged to LDS once
// (19.5 KB, covered by the A barrier) -> phase C taps are ds_reads, no L2
// chains; (2) phase D explicit double-buffered WB prefetch (full unroll,
// compile-time indices); (3) launch_bounds(256,3) -> 168 VGPR for
// pipelining. LDS 51.7 KB -> 3 blocks/CU.
// ---------------------------------------------------------------------------
__global__ __launch_bounds__(256, 3) void fused_all(
    const float* __restrict__ x, const unsigned short* __restrict__ W1bf,
    const float* __restrict__ wsf,   // [w2q 4608 | b1f 128 | b2t 128] floats
    const unsigned short* __restrict__ WB,
    const unsigned short* __restrict__ zb, float* __restrict__ out)
{
    __shared__ unsigned short xs[36*256];    // 18,432 B, swizzled
    __shared__ unsigned short h1L[36*132];   //  9,504 B  [pos][j]
    __shared__ unsigned short h2s[16*H2S];   //  4,352 B  [pos][j]
    __shared__ float sw[4864];               // 19,456 B: w2s|b1s|bs

    const int tid = threadIdx.x;
    // XCD-aware swizzle: 1568 = 8 xcd * 196; 196 = one 14x14 image.
    int bid = blockIdx.x;
    int wg = (bid & 7) * 196 + (bid >> 3);
    const int xb = wg % 14;  wg /= 14;
    const int yb = wg % 14;  const int b = wg / 14;
    const int wid = tid >> 6, l = tid & 63, l15 = l & 15, quad = l >> 4;
    const int j0w = wid * 32;

    // Stage weights/biases to LDS (independent of x loads; same barrier).
#pragma unroll
    for (int it = 0; it < 19; ++it) {
        int i = it*256 + tid;
        if (i < 4864) sw[i] = wsf[i];
    }
    const float* w2s = sw;           // 4608
    const float* b1s = sw + 4608;    // 128
    const float* bs  = sw + 4736;    // 128

    // Phase A: stage x halo (36 pos x 256 ch), fp32->bf16, XOR-swizzled
#pragma unroll
    for (int it = 0; it < 5; ++it) {
        int idx = it*256 + tid;              // 1152 tasks
        int pos = idx >> 5, g = idx & 31;
        if (pos < 36) {
            int hy = (pos*43) >> 8, hx = pos - hy*6;     // pos/6
            int gy = yb*4 + hy - 1, gx = xb*4 + hx - 1;
            uint4 st; st.x = 0u; st.y = 0u; st.z = 0u; st.w = 0u;
            if (gy >= 0 && gy < HH && gx >= 0 && gx < WW) {
                const float* xp = &x[(size_t)((b*HH + gy)*WW + gx) * C + g*8];
                float4 v0 = *(const float4*)xp;
                float4 v1 = *(const float4*)(xp + 4);
                uint2 p0 = pack4_trunc(v0), p1 = pack4_trunc(v1);
                st.x = p0.x; st.y = p0.y; st.z = p1.x; st.w = p1.y;
            }
            *(uint4*)&xs[pos*256 + ((g ^ (pos & 7)) * 8)] = st;
        }
    }
    __syncthreads();

    // Phase B: s1 GEMM -> h1L (wave-private j range), jf-outer.
    union bu { uint4 u; bf16x8_t v; };
#pragma unroll
    for (int jf = 0; jf < 2; ++jf) {
        bu aw[8];
        const int wrow = j0w + jf*16 + l15;
#pragma unroll
        for (int kc = 0; kc < 8; ++kc)
            aw[kc].u = *(const uint4*)&W1bf[wrow*C + kc*32 + quad*8];
#pragma unroll
        for (int mt = 0; mt < 3; ++mt) {
            const int row = mt*16 + l15;     // halo pos (B col), 0..47
            const int rrow = (row < 36) ? row : 0;   // clamp for LDS reads
            int hy = (row*43) >> 8;          // row/6
            int hx = row - hy*6;
            int gy = yb*4 + hy - 1, gx = xb*4 + hx - 1;
            const bool valid = (row < 36) & (gy >= 0) & (gy < HH) & (gx >= 0) & (gx < WW);
            const unsigned mask = valid ? 0xFFFFFFFFu : 0u;
            f32x4_t acc = (f32x4_t){0.f,0.f,0.f,0.f};
#pragma unroll
            for (int kc = 0; kc < 8; ++kc) {
                int g = (kc*4 + quad) ^ (rrow & 7);
                bf16x8_t bb = *(const bf16x8_t*)&xs[rrow*256 + g*8];
                acc = __builtin_amdgcn_mfma_f32_16x16x32_bf16(aw[kc].v, bb, acc, 0, 0, 0);
            }
            if (row < 36) {
                int jb = j0w + jf*16 + quad*4;
                float4 bias = *(const float4*)&b1s[jb];
                float v0 = fmaxf(acc[0] + bias.x, 0.f);
                float v1 = fmaxf(acc[1] + bias.y, 0.f);
                float v2 = fmaxf(acc[2] + bias.z, 0.f);
                float v3 = fmaxf(acc[3] + bias.w, 0.f);
                uint2 o;
                o.x = ((unsigned int)f2bf(v0) | ((unsigned int)f2bf(v1) << 16)) & mask;
                o.y = ((unsigned int)f2bf(v2) | ((unsigned int)f2bf(v3) << 16)) & mask;
                *(uint2*)&h1L[row*132 + jb] = o;
            }
        }
    }
    // NO barrier: wave w reads back only the h1L columns it just wrote.

    // Phase C: grouped 3x3 conv, wave-local paths p in [8w, 8w+8).
    const int pos = l15;
    const int py = pos >> 2, px = pos & 3;
#pragma unroll
    for (int i = 0; i < 2; ++i) {
        const int q = (l >> 4) * 2 + i;
        const int p = wid*8 + q;
        float a0 = bs[p], a1 = bs[32+p], a2 = bs[64+p], a3 = bs[96+p];
#pragma unroll
        for (int ky = 0; ky < 3; ++ky) {
#pragma unroll
            for (int kx = 0; kx < 3; ++kx) {
                const float* wp = &w2s[(ky*3 + kx) * 512 + p*4];
                float4 w0 = *(const float4*)&wp[0];     // di=0
                float4 w1 = *(const float4*)&wp[128];   // di=1
                float4 w2v = *(const float4*)&wp[256];  // di=2
                float4 w3v = *(const float4*)&wp[384];  // di=3
                int hp = (py + ky)*6 + px + kx;
                uint2 hv = *(const uint2*)&h1L[hp*132 + p*4];
                float f0 = __uint_as_float(hv.x << 16);
                float f1 = __uint_as_float(hv.x & 0xffff0000u);
                float f2 = __uint_as_float(hv.y << 16);
                float f3 = __uint_as_float(hv.y & 0xffff0000u);
                a0 = fmaf(f0, w0.x, a0);  a1 = fmaf(f0, w0.y, a1);
                a2 = fmaf(f0, w0.z, a2);  a3 = fmaf(f0, w0.w, a3);
                a0 = fmaf(f1, w1.x, a0);  a1 = fmaf(f1, w1.y, a1);
                a2 = fmaf(f1, w1.z, a2);  a3 = fmaf(f1, w1.w, a3);
                a0 = fmaf(f2, w2v.x, a0); a1 = fmaf(f2, w2v.y, a1);
                a2 = fmaf(f2, w2v.z, a2); a3 = fmaf(f2, w2v.w, a3);
                a0 = fmaf(f3, w3v.x, a0); a1 = fmaf(f3, w3v.y, a1);
                a2 = fmaf(f3, w3v.z, a2); a3 = fmaf(f3, w3v.w, a3);
            }
        }
        uint2 o;
        o.x = (unsigned int)f2bf(fmaxf(a0, 0.f)) |
              ((unsigned int)f2bf(fmaxf(a1, 0.f)) << 16);
        o.y = (unsigned int)f2bf(fmaxf(a2, 0.f)) |
              ((unsigned int)f2bf(fmaxf(a3, 0.f)) << 16);
        *(uint2*)&h2s[pos*H2S + p*4] = o;
    }
    __syncthreads();

    // Phase D: stage-3 per-path 1x1 conv via MFMA (K=8: 4 h + 1.0*bias),
    // per-path relu, accumulate over 32 paths; residual + final relu.
    // Explicit double-buffered WB prefetch: loads for pp+1 issue before
    // pp's MFMAs. Full unroll -> all array indices compile-time.
    const int cb = wid * 64;
    const unsigned short* wbp;
    int pstr, cstr;
    if (quad == 0) {
        wbp = &WB[((size_t)(cb + l15)) * 8];
        pstr = C * 8;         // shorts per p
        cstr = 16 * 8;        // shorts per c-tile
    } else {
        wbp = zb;             // 16B of zeros: k-slots 8..31 contribute 0
        pstr = 0; cstr = 0;
    }

    const f32x4_t zero = (f32x4_t){0.f, 0.f, 0.f, 0.f};
    f32x4_t dacc[4];
#pragma unroll
    for (int ct = 0; ct < 4; ++ct) dacc[ct] = zero;
    const unsigned int one = 0x3f80u;        // bf16 1.0 in low half

    union bu2 { uint4 u; bf16x8_t v; };
    bu2 Ba[8], Bb[8];
    uint4 ha, hb;
    // preload pp=0
#pragma unroll
    for (int ct = 0; ct < 4; ++ct) {
        Ba[2*ct].u   = *(const uint4*)(wbp + ct*cstr);
        Ba[2*ct+1].u = *(const uint4*)(wbp + pstr + ct*cstr);
    }
    ha = *(const uint4*)&h2s[l15*H2S];

#pragma unroll
    for (int pp = 0; pp < 16; ++pp) {
        // select current/next buffers (pp compile-time under full unroll)
        bu2* Bc = (pp & 1) ? Bb : Ba;
        bu2* Bn = (pp & 1) ? Ba : Bb;
        uint4 hc = (pp & 1) ? hb : ha;
        if (pp < 15) {
            const unsigned short* pbn = wbp + (size_t)(pp+1)*2*pstr;
#pragma unroll
            for (int ct = 0; ct < 4; ++ct) {
                Bn[2*ct].u   = *(const uint4*)(pbn + ct*cstr);
                Bn[2*ct+1].u = *(const uint4*)(pbn + pstr + ct*cstr);
            }
            uint4 hn = *(const uint4*)&h2s[l15*H2S + (pp+1)*8];
            if (pp & 1) ha = hn; else hb = hn;
        }
        union au { unsigned int u[4]; bf16x8_t v; };
        au A0, A1;
        A0.u[0] = hc.x; A0.u[1] = hc.y; A0.u[2] = one; A0.u[3] = 0u;
        A1.u[0] = hc.z; A1.u[1] = hc.w; A1.u[2] = one; A1.u[3] = 0u;
#pragma unroll
        for (int ct = 0; ct < 4; ++ct) {
            f32x4_t z0 = __builtin_amdgcn_mfma_f32_16x16x32_bf16(A0.v, Bc[2*ct].v,   zero, 0, 0, 0);
            f32x4_t z1 = __builtin_amdgcn_mfma_f32_16x16x32_bf16(A1.v, Bc[2*ct+1].v, zero, 0, 0, 0);
#pragma unroll
            for (int r = 0; r < 4; ++r)
                dacc[ct][r] += fmaxf(z0[r], 0.f) + fmaxf(z1[r], 0.f);
        }
    }

    // Epilogue: out = relu(sum + x), fp32 residual.
#pragma unroll
    for (int r = 0; r < 4; ++r) {
        int nl = quad*4 + r;                 // interior pos 0..15
        int gy = yb*4 + (nl >> 2), gx = xb*4 + (nl & 3);
        size_t n = (size_t)((b*HH + gy)*WW + gx);
        const float* xr = &x[n*C + cb + l15];
        float* orow = &out[n*C + cb + l15];
#pragma unroll
        for (int ct = 0; ct < 4; ++ct) {
            float v = dacc[ct][r] + xr[ct*16];
            orow[ct*16] = fmaxf(v, 0.f);
        }
    }
}

// ---------------------------------------------------------------------------
extern "C" void kernel_launch(void* const* d_in, const int* in_sizes, int n_in,
                              void* d_out, int out_size, void* d_ws, size_t ws_size,
                              hipStream_t stream) {
    const float* x  = (const float*)d_in[0];
    const float* W1 = (const float*)d_in[1];
    const float* B1 = (const float*)d_in[2];
    const float* W2 = (const float*)d_in[3];
    const float* B2 = (const float*)d_in[4];
    const float* W3 = (const float*)d_in[5];
    const float* B3 = (const float*)d_in[6];
    const float* G1 = (const float*)d_in[7];
    const float* Be1= (const float*)d_in[8];
    const float* M1 = (const float*)d_in[9];
    const float* V1 = (const float*)d_in[10];
    const float* G2 = (const float*)d_in[11];
    const float* Be2= (const float*)d_in[12];
    const float* M2 = (const float*)d_in[13];
    const float* V2 = (const float*)d_in[14];
    const float* G3 = (const float*)d_in[15];
    const float* Be3= (const float*)d_in[16];
    const float* M3 = (const float*)d_in[17];
    const float* V3 = (const float*)d_in[18];

    char* wsb = (char*)d_ws;
    unsigned short* W1bf = (unsigned short*)(wsb + 0);        // 65,536 B
    unsigned short* WB   = (unsigned short*)(wsb + 65536);    // 131,072 B
    float*          w2q  = (float*)(wsb + 196608);            // 18,432 B
    float*          b1f  = (float*)(wsb + 215040);            // 512 B
    float*          b2t  = (float*)(wsb + 215552);            // 512 B
    unsigned short* zb   = (unsigned short*)(wsb + 216064);   // 16 B zeros
    const float*    wsf  = (const float*)(wsb + 196608);      // w2q|b1f|b2t

    const int fold_tasks = C*J + J + 9*D*D*P + J + P*C*8 + 8; // 103,176
    fold_params<<<(fold_tasks + 255)/256, 256, 0, stream>>>(
        W1, B1, W2, B2, W3, B3, G1, Be1, M1, V1, G2, Be2, M2, V2,
        G3, Be3, M3, V3, W1bf, b1f, w2q, b2t, WB, zb);

    fused_all<<<8*14*14, 256, 0, stream>>>(x, W1bf, wsf, WB, zb,
                                           (float*)d_out);
}

// Round 8
// 167.545 us; speedup vs baseline: 3.4827x; 3.4827x over previous
//
#include <hip/hip_runtime.h>

// Problem constants
#define BATCH 8
#define HH 56
#define WW 56
#define NPOS (BATCH*HH*WW)   // 25088
#define C 256
#define P 32
#define D 4
#define J 128
#define EPS 1e-3f
#define H1S 136   // h1L stride in shorts (272B rows, 16B-aligned)
#define H2S 136   // h2s stride in shorts

typedef __attribute__((ext_vector_type(8))) short bf16x8_t;
typedef __attribute__((ext_vector_type(4))) float f32x4_t;

__device__ __forceinline__ unsigned short f2bf(float f) {
    union { float f; unsigned int i; } v; v.f = f;
    unsigned int r = v.i + 0x7fffu + ((v.i >> 16) & 1u);   // RNE
    return (unsigned short)(r >> 16);
}
__device__ __forceinline__ uint2 pack4_trunc(float4 v) {
    uint2 r;
    r.x = __builtin_amdgcn_perm(__float_as_uint(v.y), __float_as_uint(v.x), 0x07060302u);
    r.y = __builtin_amdgcn_perm(__float_as_uint(v.w), __float_as_uint(v.z), 0x07060302u);
    return r;
}

// ---------------------------------------------------------------------------
// Fold BN into conv weights/biases. NEW: wbd = block-diagonal stage-2 weight
// matrix for MFMA phase C. Layout [pg(8)][tp(5)][n(16)][k(32)] bf16:
// k = t_local*16 + p''*4 + di (tap = tp*2+t_local), n = p'*4 + do.
// Value = (p''==p' && tap<=8) ? w2[tap][pg*4+p'][di][do]*bn2scale : 0.
// ---------------------------------------------------------------------------
__global__ __launch_bounds__(256) void fold_params(
    const float* __restrict__ W1, const float* __restrict__ B1,
    const float* __restrict__ W2, const float* __restrict__ B2,
    const float* __restrict__ W3, const float* __restrict__ B3,
    const float* __restrict__ G1, const float* __restrict__ Be1,
    const float* __restrict__ M1, const float* __restrict__ V1,
    const float* __restrict__ G2, const float* __restrict__ Be2,
    const float* __restrict__ M2, const float* __restrict__ V2,
    const float* __restrict__ G3, const float* __restrict__ Be3,
    const float* __restrict__ M3, const float* __restrict__ V3,
    unsigned short* __restrict__ W1bf, float* __restrict__ b1f,
    float* __restrict__ b2t,
    unsigned short* __restrict__ WB, unsigned short* __restrict__ zb,
    unsigned short* __restrict__ wbd)
{
    int idx = blockIdx.x * 256 + threadIdx.x;

    if (idx < C*J) {                       // W1bf[j][c]
        int j = idx >> 8, c = idx & 255;
        int p = j >> 2, d = j & 3;
        float s = G1[j] * rsqrtf(V1[j] + EPS);
        W1bf[idx] = f2bf(W1[(p*C + c)*D + d] * s);
        return;
    }
    idx -= C*J;
    if (idx < J) {
        float s = G1[idx] * rsqrtf(V1[idx] + EPS);
        b1f[idx] = B1[idx] * s + Be1[idx] - M1[idx] * s;
        return;
    }
    idx -= J;
    if (idx < J) {                         // b2t[do][p]
        int do_ = idx >> 5, p = idx & 31;
        int j = p*4 + do_;
        float s = G2[j] * rsqrtf(V2[j] + EPS);
        b2t[idx] = B2[j] * s + Be2[j] - M2[j] * s;
        return;
    }
    idx -= J;
    if (idx < P*C*8) {                     // WB[p][c][s] = {w0..w3, bias, 0,0,0}
        int s8 = idx & 7;
        int c = (idx >> 3) & 255;
        int p = idx >> 11;
        float sc = G3[p*C + c] * rsqrtf(V3[p*C + c] + EPS);
        float v = 0.f;
        if (s8 < 4)       v = W3[(p*D + s8)*C + c] * sc;
        else if (s8 == 4) v = B3[p*C + c] * sc + Be3[p*C + c] - M3[p*C + c] * sc;
        WB[idx] = f2bf(v);
        return;
    }
    idx -= P*C*8;
    if (idx < 8) { zb[idx] = 0; return; }  // 16B zero block
    idx -= 8;
    if (idx < 8*5*16*32) {                 // wbd
        int k = idx & 31;
        int rest = idx >> 5;
        int n = rest & 15;
        int rest2 = rest >> 4;             // pg*5 + tp, in [0,40)
        int tp = rest2 % 5;
        int pg = rest2 / 5;
        int tap = tp*2 + (k >> 4);
        int pk = (k >> 2) & 3, di = k & 3;
        int pn = n >> 2, do_ = n & 3;
        float v = 0.f;
        if (pk == pn && tap <= 8) {
            int p = pg*4 + pn;
            int j = p*4 + do_;
            float s = G2[j] * rsqrtf(V2[j] + EPS);
            v = W2[((p*9 + tap)*4 + di)*4 + do_] * s;
        }
        wbd[idx] = f2bf(v);
        return;
    }
}

// ---------------------------------------------------------------------------
// Fully fused; phase C now MFMA (block-diagonal weights).
// r6 skeleton: tile 4x4 interior / 6x6 halo, 1568 blocks XCD-swizzled,
// 2 barriers, wave-local B->C. LDS 33.6 KB -> 4 blocks/CU.
// ---------------------------------------------------------------------------
__global__ __launch_bounds__(256, 4) void fused_all(
    const float* __restrict__ x, const unsigned short* __restrict__ W1bf,
    const float* __restrict__ wsf,   // [b1f 128 | b2t 128] floats
    const unsigned short* __restrict__ WB,
    const unsigned short* __restrict__ zb,
    const unsigned short* __restrict__ wbd,
    float* __restrict__ out)
{
    __shared__ unsigned short xs[36*256];    // 18,432 B, swizzled
    __shared__ unsigned short h1L[36*H1S];   //  9,792 B  [pos][j]
    __shared__ unsigned short h2s[16*H2S];   //  4,352 B  [pos][j]
    __shared__ float sw[256];                //  1,024 B: b1s|bs

    const int tid = threadIdx.x;
    // XCD-aware swizzle: 1568 = 8 xcd * 196; 196 = one 14x14 image.
    int bid = blockIdx.x;
    int wg = (bid & 7) * 196 + (bid >> 3);
    const int xb = wg % 14;  wg /= 14;
    const int yb = wg % 14;  const int b = wg / 14;
    const int wid = tid >> 6, l = tid & 63, l15 = l & 15, quad = l >> 4;
    const int j0w = wid * 32;

    if (tid < 256) { /* always true; keeps staging simple */ }
    if (tid < 256) sw[tid] = wsf[tid];
    const float* b1s = sw;           // 128
    const float* bs  = sw + 128;     // 128

    // Phase A: stage x halo (36 pos x 256 ch), fp32->bf16, XOR-swizzled
#pragma unroll
    for (int it = 0; it < 5; ++it) {
        int idx = it*256 + tid;              // 1152 tasks
        int pos = idx >> 5, g = idx & 31;
        if (pos < 36) {
            int hy = (pos*43) >> 8, hx = pos - hy*6;     // pos/6
            int gy = yb*4 + hy - 1, gx = xb*4 + hx - 1;
            uint4 st; st.x = 0u; st.y = 0u; st.z = 0u; st.w = 0u;
            if (gy >= 0 && gy < HH && gx >= 0 && gx < WW) {
                const float* xp = &x[(size_t)((b*HH + gy)*WW + gx) * C + g*8];
                float4 v0 = *(const float4*)xp;
                float4 v1 = *(const float4*)(xp + 4);
                uint2 p0 = pack4_trunc(v0), p1 = pack4_trunc(v1);
                st.x = p0.x; st.y = p0.y; st.z = p1.x; st.w = p1.y;
            }
            *(uint4*)&xs[pos*256 + ((g ^ (pos & 7)) * 8)] = st;
        }
    }
    __syncthreads();

    // Phase B: s1 GEMM -> h1L (wave-private j range), jf-outer.
    union bu { uint4 u; bf16x8_t v; };
#pragma unroll
    for (int jf = 0; jf < 2; ++jf) {
        bu aw[8];
        const int wrow = j0w + jf*16 + l15;
#pragma unroll
        for (int kc = 0; kc < 8; ++kc)
            aw[kc].u = *(const uint4*)&W1bf[wrow*C + kc*32 + quad*8];
#pragma unroll
        for (int mt = 0; mt < 3; ++mt) {
            const int row = mt*16 + l15;     // halo pos (B col), 0..47
            const int rrow = (row < 36) ? row : 0;   // clamp for LDS reads
            int hy = (row*43) >> 8;          // row/6
            int hx = row - hy*6;
            int gy = yb*4 + hy - 1, gx = xb*4 + hx - 1;
            const bool valid = (row < 36) & (gy >= 0) & (gy < HH) & (gx >= 0) & (gx < WW);
            const unsigned mask = valid ? 0xFFFFFFFFu : 0u;
            f32x4_t acc = (f32x4_t){0.f,0.f,0.f,0.f};
#pragma unroll
            for (int kc = 0; kc < 8; ++kc) {
                int g = (kc*4 + quad) ^ (rrow & 7);
                bf16x8_t bb = *(const bf16x8_t*)&xs[rrow*256 + g*8];
                acc = __builtin_amdgcn_mfma_f32_16x16x32_bf16(aw[kc].v, bb, acc, 0, 0, 0);
            }
            if (row < 36) {
                int jb = j0w + jf*16 + quad*4;
                float4 bias = *(const float4*)&b1s[jb];
                float v0 = fmaxf(acc[0] + bias.x, 0.f);
                float v1 = fmaxf(acc[1] + bias.y, 0.f);
                float v2 = fmaxf(acc[2] + bias.z, 0.f);
                float v3 = fmaxf(acc[3] + bias.w, 0.f);
                uint2 o;
                o.x = ((unsigned int)f2bf(v0) | ((unsigned int)f2bf(v1) << 16)) & mask;
                o.y = ((unsigned int)f2bf(v2) | ((unsigned int)f2bf(v3) << 16)) & mask;
                *(uint2*)&h1L[row*H1S + jb] = o;
            }
        }
    }
    // NO barrier: wave w reads back only the h1L columns it just wrote.

    // Phase C: grouped 3x3 conv via block-diagonal MFMA.
    // Wave w handles p-groups {2w, 2w+1} (paths 8w..8w+8).
    // A[pos][k=(t_local, j16)]: lane row=l15=pos, k=quad*8+j ->
    //   tap = tp*2 + (quad>>1), j_local = pg*16 + (quad&1)*8 + j (b128 read).
    // B from wbd (global, L2-hot, block-invariant).
    // D[row=quad*4+r][col=l15=(p',do)] -> h2s[row][pg*16 + l15].
    {
        const int pos = l15, py = pos >> 2, px = pos & 3;
#pragma unroll
        for (int ig = 0; ig < 2; ++ig) {
            const int pg = wid*2 + ig;
            const int pD = pg*4 + (l15 >> 2), doD = l15 & 3;
            const float bias = bs[doD*32 + pD];
            f32x4_t cacc = (f32x4_t){bias, bias, bias, bias};
#pragma unroll
            for (int tp = 0; tp < 5; ++tp) {
                int tap = tp*2 + (quad >> 1);
                if (tap > 8) tap = 8;        // B rows are zero for tap 9
                int ky = (tap*11) >> 5;      // tap/3
                int kx = tap - ky*3;
                int hp = (py + ky)*6 + px + kx;
                bf16x8_t av = *(const bf16x8_t*)&h1L[hp*H1S + pg*16 + (quad & 1)*8];
                bf16x8_t bv = *(const bf16x8_t*)&wbd[(((pg*5 + tp)*16 + l15) << 5) + quad*8];
                cacc = __builtin_amdgcn_mfma_f32_16x16x32_bf16(av, bv, cacc, 0, 0, 0);
            }
#pragma unroll
            for (int r = 0; r < 4; ++r)
                h2s[(quad*4 + r)*H2S + pg*16 + l15] = f2bf(fmaxf(cacc[r], 0.f));
        }
    }
    __syncthreads();

    // Phase D: stage-3 per-path 1x1 conv via MFMA (K=8: 4 h + 1.0*bias),
    // per-path relu, accumulate over 32 paths; residual + final relu.
    const int cb = wid * 64;
    const unsigned short* wbp;
    int pstr, cstr;
    if (quad == 0) {
        wbp = &WB[((size_t)(cb + l15)) * 8];
        pstr = C * 8;         // shorts per p
        cstr = 16 * 8;        // shorts per c-tile
    } else {
        wbp = zb;             // 16B of zeros: k-slots 8..31 contribute 0
        pstr = 0; cstr = 0;
    }

    const f32x4_t zero = (f32x4_t){0.f, 0.f, 0.f, 0.f};
    f32x4_t dacc[4];
#pragma unroll
    for (int ct = 0; ct < 4; ++ct) dacc[ct] = zero;
    const unsigned int one = 0x3f80u;        // bf16 1.0 in low half

#pragma unroll 2
    for (int pp = 0; pp < 16; ++pp) {        // p = 2*pp, 2*pp+1
        uint4 h0 = *(const uint4*)&h2s[l15*H2S + pp*8];
        union au { unsigned int u[4]; bf16x8_t v; };
        au A0, A1;
        A0.u[0] = h0.x; A0.u[1] = h0.y; A0.u[2] = one; A0.u[3] = 0u;
        A1.u[0] = h0.z; A1.u[1] = h0.w; A1.u[2] = one; A1.u[3] = 0u;
        const unsigned short* pb0 = wbp + pp*2*pstr;
        const unsigned short* pb1 = pb0 + pstr;
#pragma unroll
        for (int ct = 0; ct < 4; ++ct) {
            union bu2 { uint4 u; bf16x8_t v; } B0, B1;
            B0.u = *(const uint4*)(pb0 + ct*cstr);
            B1.u = *(const uint4*)(pb1 + ct*cstr);
            f32x4_t z0 = __builtin_amdgcn_mfma_f32_16x16x32_bf16(A0.v, B0.v, zero, 0, 0, 0);
            f32x4_t z1 = __builtin_amdgcn_mfma_f32_16x16x32_bf16(A1.v, B1.v, zero, 0, 0, 0);
#pragma unroll
            for (int r = 0; r < 4; ++r)
                dacc[ct][r] += fmaxf(z0[r], 0.f) + fmaxf(z1[r], 0.f);
        }
    }

    // Epilogue: out = relu(sum + x), fp32 residual.
#pragma unroll
    for (int r = 0; r < 4; ++r) {
        int nl = quad*4 + r;                 // interior pos 0..15
        int gy = yb*4 + (nl >> 2), gx = xb*4 + (nl & 3);
        size_t n = (size_t)((b*HH + gy)*WW + gx);
        const float* xr = &x[n*C + cb + l15];
        float* orow = &out[n*C + cb + l15];
#pragma unroll
        for (int ct = 0; ct < 4; ++ct) {
            float v = dacc[ct][r] + xr[ct*16];
            orow[ct*16] = fmaxf(v, 0.f);
        }
    }
}

// ---------------------------------------------------------------------------
extern "C" void kernel_launch(void* const* d_in, const int* in_sizes, int n_in,
                              void* d_out, int out_size, void* d_ws, size_t ws_size,
                              hipStream_t stream) {
    const float* x  = (const float*)d_in[0];
    const float* W1 = (const float*)d_in[1];
    const float* B1 = (const float*)d_in[2];
    const float* W2 = (const float*)d_in[3];
    const float* B2 = (const float*)d_in[4];
    const float* W3 = (const float*)d_in[5];
    const float* B3 = (const float*)d_in[6];
    const float* G1 = (const float*)d_in[7];
    const float* Be1= (const float*)d_in[8];
    const float* M1 = (const float*)d_in[9];
    const float* V1 = (const float*)d_in[10];
    const float* G2 = (const float*)d_in[11];
    const float* Be2= (const float*)d_in[12];
    const float* M2 = (const float*)d_in[13];
    const float* V2 = (const float*)d_in[14];
    const float* G3 = (const float*)d_in[15];
    const float* Be3= (const float*)d_in[16];
    const float* M3 = (const float*)d_in[17];
    const float* V3 = (const float*)d_in[18];

    char* wsb = (char*)d_ws;
    unsigned short* W1bf = (unsigned short*)(wsb + 0);        // 65,536 B
    unsigned short* WB   = (unsigned short*)(wsb + 65536);    // 131,072 B
    float*          b1f  = (float*)(wsb + 196608);            // 512 B
    float*          b2t  = (float*)(wsb + 197120);            // 512 B
    unsigned short* zb   = (unsigned short*)(wsb + 197632);   // 16 B zeros
    unsigned short* wbd  = (unsigned short*)(wsb + 197648);   // 40,960 B
    const float*    wsf  = (const float*)(wsb + 196608);      // b1f|b2t

    const int fold_tasks = C*J + J + J + P*C*8 + 8 + 8*5*16*32; // 119,304
    fold_params<<<(fold_tasks + 255)/256, 256, 0, stream>>>(
        W1, B1, W2, B2, W3, B3, G1, Be1, M1, V1, G2, Be2, M2, V2,
        G3, Be3, M3, V3, W1bf, b1f, b2t, WB, zb, wbd);

    fused_all<<<8*14*14, 256, 0, stream>>>(x, W1bf, wsf, WB, zb, wbd,
                                           (float*)d_out);
}